// Round 8
// baseline (296.755 us; speedup 1.0000x reference)
//
#include <hip/hip_runtime.h>
#include <hip/hip_cooperative_groups.h>
namespace cg = cooperative_groups;

constexpr int ATOM = 34;
constexpr int HID = 256;
constexpr int LATENT = 128;
constexpr int CELLS = 512;
constexpr int NN = 128;
constexpr int NA = NN * ATOM;   // 4352
#define NEGF (-9e15f)

// ---- LDS pool layout (floats) ----
constexpr int P_XL   = 0;       // [128][36] = 4608   (GAT x, full batch)
constexpr int P_HLT  = 4608;    // [34][132] = 4488   (h transposed)
constexpr int P_ATT  = 9096;    // [32][132] = 4224   (att, stride 132: no 4-way conflict)
constexpr int P_MASK = 13320;   // u64[32][2] = 128 floats (adjacency bitmasks, persist r0->r2)
constexpr int P_FS   = 13448;   // 128
constexpr int P_FD   = 13576;   // 128 -> 13704
// phaseB overlays (xl/hlT/att dead):
constexpr int P_WT   = 0;       // [256][36] = 9216   (pl[8][32][34]=8704 overlays after weights dead)
constexpr int P_WF   = 9216;    // [256][36] = 9216 -> 18432
constexpr int P_DLT  = 18432;   // [34][33] = 1122 -> 19554
constexpr int P_SL   = 19554;   // 512 -> 20066
// survives GAT->phaseB:
constexpr int P_XQ   = 20100;   // [32][36] = 1152 -> 21252
// decoder overlays:
constexpr int P_VEC  = 0;       // 640
constexpr int P_DSL  = 640;     // 512
constexpr int P_H1   = 1152;    // 128
constexpr int P_H2   = 1280;    // 256
constexpr int POOL   = 21252;   // 85.0 KB -> 1 block/CU, 256 blocks co-resident

__global__ __launch_bounds__(512, 2) void mega(
    const float* __restrict__ xs, const int* __restrict__ A,
    const float* __restrict__ cell,
    const float* __restrict__ Wg3, const float* __restrict__ bg3,
    const float* __restrict__ av3,
    const float* __restrict__ Wt, const float* __restrict__ bt,
    const float* __restrict__ Wf, const float* __restrict__ bf,
    const float* __restrict__ Wf2, const float* __restrict__ bf2,
    const float* __restrict__ W1, const float* __restrict__ b1,
    const float* __restrict__ W2, const float* __restrict__ b2,
    const float* __restrict__ W3, const float* __restrict__ b3,
    const float* __restrict__ W4, const float* __restrict__ b4,
    float* __restrict__ out, float* __restrict__ X0, float* __restrict__ X1,
    float* __restrict__ DM)
{
    cg::grid_group grid = cg::this_grid();
    __shared__ __align__(16) float pool[POOL];
    const int bid = blockIdx.x, b = bid >> 2, q4 = bid & 3;
    const int t = threadIdx.x, lane = t & 63, wave = t >> 6;
    const int p0 = q4 * 32;

    float* xl  = pool + P_XL;
    float* hlT = pool + P_HLT;
    float* att = pool + P_ATT;
    unsigned long long* mask = (unsigned long long*)(pool + P_MASK);
    float* fs  = pool + P_FS;
    float* fd  = pool + P_FD;
    float* xq  = pool + P_XQ;

    // wave-uniform helpers (force SGPR so weight reads become s_load)
    const int halfU = __builtin_amdgcn_readfirstlane(t >> 7);  // 0..3
    const int waveU = __builtin_amdgcn_readfirstlane(wave);    // 0..7
    const int nIdx  = t & 127;

    // xl pads (persist; staging only rewrites cols 0..33)
    if (t < 256) xl[(t >> 1) * 36 + 34 + (t & 1)] = 0.f;

    // =================== 3 GAT rounds ===================
    for (int r = 0; r < 3; ++r) {
        const float* Wgr = Wg3 + r * ATOM * ATOM;
        const float* bgr = bg3 + r * ATOM;
        const float* avr = av3 + r * 2 * ATOM;
        const float* xsrc = (r == 0) ? (xs + b * NA) : (((r == 1) ? X0 : X1) + b * NA);

        for (int i = t; i < NA; i += 512) xl[(i / ATOM) * 36 + (i % ATOM)] = xsrc[i];
        __syncthreads();

        // h^T = relu(x@Wg+bg)^T : (n = t&127, e-quarter = halfU) — weights via scalar loads
        {
            float xr[36];
            {
                float4* x4 = (float4*)xr;
                const float4* p4 = (const float4*)(xl + nIdx * 36);
                #pragma unroll
                for (int k = 0; k < 9; ++k) x4[k] = p4[k];
            }
            #pragma unroll
            for (int j = 0; j < 9; ++j) {
                const int e = halfU * 9 + j;          // wave-uniform
                if (e < ATOM) {
                    float acc = bgr[e];
                    #pragma unroll
                    for (int d = 0; d < ATOM; ++d) acc += xr[d] * Wgr[d * ATOM + e];
                    hlT[e * 132 + nIdx] = fmaxf(acc, 0.f);
                }
            }
        }
        __syncthreads();

        // fs/fd (waves 0-3)
        if (halfU < 2) {
            const float* avp = avr + halfU * ATOM;    // uniform -> s_load
            float acc = 0.f;
            #pragma unroll
            for (int d = 0; d < ATOM; ++d) acc += hlT[d * 132 + nIdx] * avp[d];
            if (halfU == 0) fs[nIdx] = acc; else fd[nIdx] = acc;
        }
        __syncthreads();

        // masked softmax: 8 waves x 4 rows; masks built once (r==0)
        const int* Ab = A + b * NN * NN;
        #pragma unroll
        for (int i = 0; i < 4; ++i) {
            const int lp = wave * 4 + i, gp = p0 + lp;
            unsigned long long m0, m1;
            if (r == 0) {
                m0 = __ballot(Ab[gp * NN + lane] > 0);
                m1 = __ballot(Ab[gp * NN + 64 + lane] > 0);
                if (lane == 0) { mask[lp * 2] = m0; mask[lp * 2 + 1] = m1; }
            } else {
                m0 = mask[lp * 2]; m1 = mask[lp * 2 + 1];
            }
            float fsv = fs[gp];
            float s0 = fsv + fd[lane];
            s0 = (s0 > 0.f) ? s0 : 0.01f * s0;
            if (!((m0 >> lane) & 1ull)) s0 = NEGF;
            float s1 = fsv + fd[64 + lane];
            s1 = (s1 > 0.f) ? s1 : 0.01f * s1;
            if (!((m1 >> lane) & 1ull)) s1 = NEGF;
            float mx = fmaxf(s0, s1);
            #pragma unroll
            for (int o = 32; o >= 1; o >>= 1) mx = fmaxf(mx, __shfl_xor(mx, o, 64));
            float e0 = __expf(s0 - mx), e1 = __expf(s1 - mx);
            float sm = e0 + e1;
            #pragma unroll
            for (int o = 32; o >= 1; o >>= 1) sm += __shfl_xor(sm, o, 64);
            float inv = 1.f / sm;
            att[lp * 132 + lane]      = e0 * inv;
            att[lp * 132 + 64 + lane] = e1 * inv;
        }
        __syncthreads();

        // x_out = x + att@h : (p = t>>4, g = t&15)
        {
            const int p = t >> 4, g = t & 15, gp = p0 + p;
            const float4* ap  = (const float4*)(att + p * 132);
            const float4* h1p = (const float4*)(hlT + g * 132);
            const float4* h2p = (const float4*)(hlT + (g + 16) * 132);
            float a1 = 0.f, a2 = 0.f;
            #pragma unroll 8
            for (int k = 0; k < 32; ++k) {
                float4 a4 = ap[k], x1 = h1p[k], x2 = h2p[k];
                a1 += a4.x * x1.x + a4.y * x1.y + a4.z * x1.z + a4.w * x1.w;
                a2 += a4.x * x2.x + a4.y * x2.y + a4.z * x2.z + a4.w * x2.w;
            }
            float a3 = 0.f;
            if (g < 2) {
                const float4* h3p = (const float4*)(hlT + (g + 32) * 132);
                #pragma unroll 8
                for (int k = 0; k < 32; ++k) {
                    float4 a4 = ap[k], x3 = h3p[k];
                    a3 += a4.x * x3.x + a4.y * x3.y + a4.z * x3.z + a4.w * x3.w;
                }
            }
            if (r < 2) {
                float* Xr = ((r == 0) ? X0 : X1) + b * NA + gp * ATOM;
                Xr[g]      = xl[gp * 36 + g] + a1;
                Xr[g + 16] = xl[gp * 36 + g + 16] + a2;
                if (g < 2) Xr[g + 32] = xl[gp * 36 + g + 32] + a3;
            } else {                                  // round 3: keep in LDS
                xq[p * 36 + g]      = xl[gp * 36 + g] + a1;
                xq[p * 36 + g + 16] = xl[gp * 36 + g + 16] + a2;
                if (g < 2) {
                    xq[p * 36 + g + 32] = xl[gp * 36 + g + 32] + a3;
                    xq[p * 36 + 34 + g] = 0.f;        // zero pads
                }
            }
        }
        if (r < 2) grid.sync();
    }
    __syncthreads();     // xq ready; xl/hlT/att/mask dead -> overlay

    // =================== phaseB ===================
    float* wt  = pool + P_WT;
    float* wf  = pool + P_WF;
    float* pl  = pool + P_WT;      // overlays wt after weights consumed
    float* dlT = pool + P_DLT;
    float* sl  = pool + P_SL;

    for (int i = t; i < ATOM * HID; i += 512) {
        int d = i >> 8, h = i & 255;               // Wt is [d][h]
        wt[h * 36 + d] = Wt[i];
    }
    for (int i = t; i < HID * ATOM; i += 512) {
        int h = i / ATOM, j = i - (i / ATOM) * ATOM; // Wf is [h][j]
        wf[h * 36 + j] = Wf[i];
    }
    wt[(t >> 1) * 36 + 34 + (t & 1)] = 0.f;        // zero pads (512 = 256h x 2)
    wf[(t >> 1) * 36 + 34 + (t & 1)] = 0.f;
    __syncthreads();

    // g = relu(x@Wt+bt); dp = g@Wf : thread (rp = t&15 -> rows rp & rp+16, sub = t>>4)
    {
        const int rp = t & 15, sub = t >> 4, s2 = (lane >> 4);   // sub = 4*wave + s2
        float xrA[36], xrB[36], dpA[36], dpB[36];
        {
            float4* a4 = (float4*)xrA; float4* b4v = (float4*)xrB;
            const float4* pa = (const float4*)(xq + rp * 36);
            const float4* pb = (const float4*)(xq + (rp + 16) * 36);
            #pragma unroll
            for (int k = 0; k < 9; ++k) { a4[k] = pa[k]; b4v[k] = pb[k]; }
        }
        #pragma unroll
        for (int j = 0; j < 36; ++j) { dpA[j] = 0.f; dpB[j] = 0.f; }
        #pragma unroll
        for (int i = 0; i < 8; ++i) {
            const int h = sub + 32 * i;
            const float4* wtp = (const float4*)(wt + h * 36);
            float a = 0.f, c = 0.f;
            #pragma unroll
            for (int k = 0; k < 9; ++k) {
                float4 w4 = wtp[k];
                a += xrA[4*k] * w4.x + xrA[4*k+1] * w4.y + xrA[4*k+2] * w4.z + xrA[4*k+3] * w4.w;
                c += xrB[4*k] * w4.x + xrB[4*k+1] * w4.y + xrB[4*k+2] * w4.z + xrB[4*k+3] * w4.w;
            }
            const float btv = bt[h];
            const float gA = fmaxf(a + btv, 0.f), gB = fmaxf(c + btv, 0.f);
            const float4* wfp = (const float4*)(wf + h * 36);
            #pragma unroll
            for (int k = 0; k < 9; ++k) {
                float4 w4 = wfp[k];
                dpA[4*k]   += gA * w4.x; dpA[4*k+1] += gA * w4.y;
                dpA[4*k+2] += gA * w4.z; dpA[4*k+3] += gA * w4.w;
                dpB[4*k]   += gB * w4.x; dpB[4*k+1] += gB * w4.y;
                dpB[4*k+2] += gB * w4.z; dpB[4*k+3] += gB * w4.w;
            }
        }
        __syncthreads();    // wt/wf weights fully consumed -> pl overlay safe
        // combine 4 subs of this wave via shfl, lanes 0..15 store
        #pragma unroll
        for (int j = 0; j < ATOM; ++j) {
            float a = dpA[j];
            a += __shfl_xor(a, 16, 64); a += __shfl_xor(a, 32, 64);
            float c = dpB[j];
            c += __shfl_xor(c, 16, 64); c += __shfl_xor(c, 32, 64);
            if (s2 == 0) {
                pl[(waveU * 32 + rp) * ATOM + j]      = a;
                pl[(waveU * 32 + rp + 16) * ATOM + j] = c;
            }
        }
    }
    __syncthreads();

    // d = sum_w(pl) + bf + xs ; store transposed
    {
        const float* xsq = xs + b * NA + p0 * ATOM;
        for (int i = t; i < 32 * ATOM; i += 512) {
            int rr = i / ATOM, j = i - rr * ATOM;
            float dv = bf[j] + xsq[rr * ATOM + j];
            #pragma unroll
            for (int w = 0; w < 8; ++w) dv += pl[(w * 32 + rr) * ATOM + j];
            dlT[j * 33 + rr] = dv;
        }
    }
    __syncthreads();

    // d @ Wf2 + bf2 ; partial col-max (4 chunks x 8 rows); Wf2 direct from L2 (coalesced)
    {
        const int l = t & 127, chunk = t >> 7;
        float w2r[ATOM];
        #pragma unroll
        for (int j = 0; j < ATOM; ++j) w2r[j] = Wf2[j * LATENT + l];
        const float bb = bf2[l];
        float mx = -3.4e38f;
        #pragma unroll
        for (int r8 = 0; r8 < 8; ++r8) {
            const int rr = chunk * 8 + r8;
            float acc = bb;
            #pragma unroll
            for (int j = 0; j < ATOM; ++j) acc += dlT[j * 33 + rr] * w2r[j];
            mx = fmaxf(mx, acc);
        }
        sl[chunk * 128 + l] = mx;
    }
    __syncthreads();
    if (t < LATENT)
        DM[(b * 4 + q4) * LATENT + t] =
            fmaxf(fmaxf(sl[t], sl[128 + t]), fmaxf(sl[256 + t], sl[384 + t]));

    grid.sync();

    // =================== decoder (blocks with q4==0) ===================
    if (q4 != 0) return;
    float* vec = pool + P_VEC;
    float* dsl = pool + P_DSL;
    float* h1  = pool + P_H1;
    float* h2  = pool + P_H2;

    if (t < LATENT) {
        float m = fmaxf(fmaxf(DM[(b*4+0)*LATENT + t], DM[(b*4+1)*LATENT + t]),
                        fmaxf(DM[(b*4+2)*LATENT + t], DM[(b*4+3)*LATENT + t]));
        vec[t] = 1.f / (1.f + __expf(-m));
    }
    vec[LATENT + t] = 1.f / (1.f + __expf(-cell[b * CELLS + t]));
    __syncthreads();
    {   // L1: 640->128, 4-way k-split
        const int j = t & 127, part = t >> 7;
        float acc = 0.f;
        #pragma unroll 8
        for (int k = part * 160; k < part * 160 + 160; ++k)
            acc += vec[k] * W1[k * 128 + j];
        dsl[part * 128 + j] = acc;
    }
    __syncthreads();
    if (t < 128)
        h1[t] = fmaxf(dsl[t] + dsl[128 + t] + dsl[256 + t] + dsl[384 + t] + b1[t], 0.f);
    __syncthreads();
    {   // L2: 128->256, 2-way k-split
        const int j = t & 255, half = t >> 8;
        float acc = 0.f;
        #pragma unroll 8
        for (int k = half * 64; k < half * 64 + 64; ++k)
            acc += h1[k] * W2[k * 256 + j];
        dsl[half * 256 + j] = acc;
    }
    __syncthreads();
    if (t < 256) h2[t] = fmaxf(dsl[t] + dsl[256 + t] + b2[t], 0.f);
    __syncthreads();
    {   // L3 + L4
        float acc = b3[t];
        #pragma unroll 8
        for (int k = 0; k < 256; ++k) acc += h2[k] * W3[k * 512 + t];
        float v = fmaxf(acc, 0.f) * W4[t];
        #pragma unroll
        for (int o = 32; o >= 1; o >>= 1) v += __shfl_xor(v, o, 64);
        if (lane == 0) dsl[wave] = v;
    }
    __syncthreads();
    if (t == 0) {
        float s = b4[0];
        #pragma unroll
        for (int w = 0; w < 8; ++w) s += dsl[w];
        out[b] = s;
    }
}

extern "C" void kernel_launch(void* const* d_in, const int* in_sizes, int n_in,
                              void* d_out, int out_size, void* d_ws, size_t ws_size,
                              hipStream_t stream) {
    const float* xs       = (const float*)d_in[0];
    const int*   A        = (const int*)  d_in[1];
    const float* cell_emb = (const float*)d_in[2];
    const float* Wg       = (const float*)d_in[3];
    const float* bg       = (const float*)d_in[4];
    const float* attnv    = (const float*)d_in[5];
    const float* Wt       = (const float*)d_in[6];
    const float* bt       = (const float*)d_in[7];
    const float* Wf       = (const float*)d_in[8];
    const float* bf       = (const float*)d_in[9];
    const float* Wf2      = (const float*)d_in[10];
    const float* bf2      = (const float*)d_in[11];
    const float* W1       = (const float*)d_in[12];
    const float* b1       = (const float*)d_in[13];
    const float* W2       = (const float*)d_in[14];
    const float* b2       = (const float*)d_in[15];
    const float* W3       = (const float*)d_in[16];
    const float* b3       = (const float*)d_in[17];
    const float* W4       = (const float*)d_in[18];
    const float* b4       = (const float*)d_in[19];
    float* out = (float*)d_out;

    float* Wsp = (float*)d_ws;
    float* X0 = Wsp;                 // 64*4352
    float* X1 = Wsp + 278528;        // 64*4352
    float* DM = Wsp + 557056;        // 64*4*128

    void* kargs[] = {
        (void*)&xs, (void*)&A, (void*)&cell_emb,
        (void*)&Wg, (void*)&bg, (void*)&attnv,
        (void*)&Wt, (void*)&bt, (void*)&Wf, (void*)&bf,
        (void*)&Wf2, (void*)&bf2,
        (void*)&W1, (void*)&b1, (void*)&W2, (void*)&b2,
        (void*)&W3, (void*)&b3, (void*)&W4, (void*)&b4,
        (void*)&out, (void*)&X0, (void*)&X1, (void*)&DM
    };
    hipLaunchCooperativeKernel((void*)mega, dim3(256), dim3(512), kargs, 0, stream);
}

// Round 9
// 208.159 us; speedup vs baseline: 1.4256x; 1.4256x over previous
//
#include <hip/hip_runtime.h>

constexpr int ATOM = 34;
constexpr int HID = 256;
constexpr int LATENT = 128;
constexpr int CELLS = 512;
constexpr int NN = 128;
constexpr int NA = NN * ATOM;   // 4352
#define NEGF (-9e15f)

// ---------------- K0: prep — adjacency bitmasks + transposed Wg ----------------
// blocks 0..63: masks for batch b.  block 64: WgT3[r][e][36] = Wg[r][d][e], pads 0.
__global__ __launch_bounds__(256) void k_prep(
    const int* __restrict__ A, const float* __restrict__ Wg3,
    unsigned long long* __restrict__ M, float* __restrict__ WgT3)
{
    const int blk = blockIdx.x, t = threadIdx.x, lane = t & 63, wave = t >> 6;
    if (blk < 64) {
        const int* Ab = A + blk * NN * NN;
        unsigned long long* Mb = M + blk * NN * 2;
        for (int i = 0; i < 32; ++i) {
            const int row = wave * 32 + i;
            unsigned long long m0 = __ballot(Ab[row * NN + lane] > 0);
            unsigned long long m1 = __ballot(Ab[row * NN + 64 + lane] > 0);
            if (lane == 0) { Mb[row * 2] = m0; Mb[row * 2 + 1] = m1; }
        }
    } else {
        for (int i = t; i < 3 * ATOM * 36; i += 256) {
            const int r = i / (ATOM * 36), rem = i - r * ATOM * 36;
            const int e = rem / 36, d = rem - e * 36;
            WgT3[i] = (d < ATOM) ? Wg3[r * ATOM * ATOM + d * ATOM + e] : 0.f;
        }
    }
}

// ---------------- K1: fused GAT round ----------------
// grid 512 = 64 batches x 8 slices of 16 rows, block 256 (4 waves).
// Wg weights read through the SCALAR pipe (e wave-uniform), masks precomputed.
__global__ __launch_bounds__(256, 2) void k_gat(
    const float* __restrict__ xsrc, const unsigned long long* __restrict__ M,
    const float* __restrict__ WgTr, const float* __restrict__ bgr,
    const float* __restrict__ avr, float* __restrict__ X)
{
    const int b = blockIdx.x >> 3, s8 = blockIdx.x & 7;
    const int t = threadIdx.x, lane = t & 63, wave = t >> 6;
    const int p0 = s8 * 16;

    __shared__ __align__(16) float xl[NN * 36];      // 18.4 KB
    __shared__ __align__(16) float hlT[ATOM * 132];  // 17.9 KB  h transposed
    __shared__ __align__(16) float att[16 * 132];    // 8.4 KB   stride 132: no 4-way conflict
    __shared__ float fs[NN], fd[NN];

    // ---- stage x ----
    const float* xp = xsrc + b * NA;
    for (int i = t; i < NA; i += 256) xl[(i / ATOM) * 36 + (i % ATOM)] = xp[i];
    xl[(t >> 1) * 36 + 34 + (t & 1)] = 0.f;          // zero pads (256 slots)
    __syncthreads();

    // ---- h^T = relu(x @ Wg + bg)^T : n = t&127, e-half wave-uniform ----
    {
        const int n = t & 127;
        const int eh = __builtin_amdgcn_readfirstlane(t >> 7);  // 0/1, uniform
        float xr[36];
        {
            float4* x4 = (float4*)xr;
            const float4* p4 = (const float4*)(xl + n * 36);
            #pragma unroll
            for (int k = 0; k < 9; ++k) x4[k] = p4[k];
        }
        #pragma unroll
        for (int j = 0; j < 17; ++j) {
            const int e = eh * 17 + j;                // scalar
            const float* wp = WgTr + e * 36;          // scalar address -> s_load
            float acc = bgr[e];
            #pragma unroll
            for (int d = 0; d < ATOM; ++d) acc += xr[d] * wp[d];
            hlT[e * 132 + n] = fmaxf(acc, 0.f);
        }
    }
    __syncthreads();

    // ---- fs/fd (all 256 threads: 2 x 128) ----
    {
        const int n = t & 127, w = t >> 7;
        const float* avp = avr + w * ATOM;
        float acc = 0.f;
        #pragma unroll
        for (int d = 0; d < ATOM; ++d) acc += hlT[d * 132 + n] * avp[d];
        if (w == 0) fs[n] = acc; else fd[n] = acc;
    }
    __syncthreads();

    // ---- masked softmax: 4 waves x 4 rows (precomputed masks) ----
    const unsigned long long* Mb = M + b * NN * 2;
    #pragma unroll
    for (int i = 0; i < 4; ++i) {
        const int lp = wave * 4 + i, gp = p0 + lp;
        const unsigned long long m0 = Mb[gp * 2];     // uniform -> s_load
        const unsigned long long m1 = Mb[gp * 2 + 1];
        const float fsv = fs[gp];
        float s0 = fsv + fd[lane];
        s0 = (s0 > 0.f) ? s0 : 0.01f * s0;
        if (!((m0 >> lane) & 1ull)) s0 = NEGF;
        float s1 = fsv + fd[64 + lane];
        s1 = (s1 > 0.f) ? s1 : 0.01f * s1;
        if (!((m1 >> lane) & 1ull)) s1 = NEGF;
        float mx = fmaxf(s0, s1);
        #pragma unroll
        for (int o = 32; o >= 1; o >>= 1) mx = fmaxf(mx, __shfl_xor(mx, o, 64));
        float e0 = __expf(s0 - mx), e1 = __expf(s1 - mx);
        float sm = e0 + e1;
        #pragma unroll
        for (int o = 32; o >= 1; o >>= 1) sm += __shfl_xor(sm, o, 64);
        float inv = 1.f / sm;
        att[lp * 132 + lane]      = e0 * inv;
        att[lp * 132 + 64 + lane] = e1 * inv;
    }
    __syncthreads();

    // ---- x_out = x + att @ h : thread (p = t>>4, g = t&15) ----
    {
        const int p = t >> 4, g = t & 15, gp = p0 + p;
        const float4* ap  = (const float4*)(att + p * 132);
        const float4* h1p = (const float4*)(hlT + g * 132);
        const float4* h2p = (const float4*)(hlT + (g + 16) * 132);
        float a1 = 0.f, a2 = 0.f;
        #pragma unroll 8
        for (int k = 0; k < 32; ++k) {
            float4 a4 = ap[k], x1 = h1p[k], x2 = h2p[k];
            a1 += a4.x * x1.x + a4.y * x1.y + a4.z * x1.z + a4.w * x1.w;
            a2 += a4.x * x2.x + a4.y * x2.y + a4.z * x2.z + a4.w * x2.w;
        }
        float* Xr = X + b * NA + gp * ATOM;
        Xr[g]      = xl[gp * 36 + g] + a1;
        Xr[g + 16] = xl[gp * 36 + g + 16] + a2;
        if (g < 2) {
            const float4* h3p = (const float4*)(hlT + (g + 32) * 132);
            float a3 = 0.f;
            #pragma unroll 8
            for (int k = 0; k < 32; ++k) {
                float4 a4 = ap[k], x3 = h3p[k];
                a3 += a4.x * x3.x + a4.y * x3.y + a4.z * x3.z + a4.w * x3.w;
            }
            Xr[g + 32] = xl[gp * 36 + g + 32] + a3;
        }
    }
}

// ---------------- K2: phaseB — 2-row register blocking, (512,1): no spill ----------------
// grid 256 = 64 batches x 4 quarters of 32 rows, block 512.
__global__ __launch_bounds__(512, 1) void k_phaseB(
    const float* __restrict__ X, const float* __restrict__ xs,
    const float* __restrict__ Wt, const float* __restrict__ bt,
    const float* __restrict__ Wf, const float* __restrict__ bf,
    const float* __restrict__ Wf2, const float* __restrict__ bf2,
    float* __restrict__ DM)
{
    const int b = blockIdx.x >> 2, q4 = blockIdx.x & 3;
    const int t = threadIdx.x, lane = t & 63, wave = t >> 6;
    const int p0 = q4 * 32;
    __shared__ __align__(16) float wt[HID * 36];   // [h][d]; reused as pl after consumption
    __shared__ __align__(16) float wf[HID * 36];   // [h][j]
    __shared__ __align__(16) float xl[32 * 36];
    __shared__ float dlT[ATOM * 33];
    __shared__ float sl[512];

    for (int i = t; i < ATOM * HID; i += 512) {
        int d = i >> 8, h = i & 255;               // Wt is [d][h]
        wt[h * 36 + d] = Wt[i];
    }
    for (int i = t; i < HID * ATOM; i += 512) {
        int h = i / ATOM, j = i - (i / ATOM) * ATOM; // Wf is [h][j]
        wf[h * 36 + j] = Wf[i];
    }
    wt[(t >> 1) * 36 + 34 + (t & 1)] = 0.f;        // zero pads (512 = 256h x 2)
    wf[(t >> 1) * 36 + 34 + (t & 1)] = 0.f;
    for (int i = t; i < 32 * ATOM; i += 512) xl[(i / ATOM) * 36 + (i % ATOM)] = X[b * NA + p0 * ATOM + i];
    if (t < 64) xl[(t >> 1) * 36 + 34 + (t & 1)] = 0.f;
    __syncthreads();

    const int waveU = __builtin_amdgcn_readfirstlane(wave);
    // g = relu(x@Wt+bt); dp = g@Wf : thread (rp = t&15 -> rows rp, rp+16; sub = t>>4)
    {
        const int rp = t & 15, sub = t >> 4, s2 = lane >> 4;   // sub = 4*wave + (s2&3)... s2 0..3
        float xrA[36], xrB[36], dpA[36], dpB[36];
        {
            float4* a4 = (float4*)xrA; float4* b4v = (float4*)xrB;
            const float4* pa = (const float4*)(xl + rp * 36);
            const float4* pb = (const float4*)(xl + (rp + 16) * 36);
            #pragma unroll
            for (int k = 0; k < 9; ++k) { a4[k] = pa[k]; b4v[k] = pb[k]; }
        }
        #pragma unroll
        for (int j = 0; j < 36; ++j) { dpA[j] = 0.f; dpB[j] = 0.f; }
        #pragma unroll
        for (int i = 0; i < 8; ++i) {
            const int h = sub + 32 * i;
            const float4* wtp = (const float4*)(wt + h * 36);
            float a = 0.f, c = 0.f;
            #pragma unroll
            for (int k = 0; k < 9; ++k) {
                float4 w4 = wtp[k];
                a += xrA[4*k] * w4.x + xrA[4*k+1] * w4.y + xrA[4*k+2] * w4.z + xrA[4*k+3] * w4.w;
                c += xrB[4*k] * w4.x + xrB[4*k+1] * w4.y + xrB[4*k+2] * w4.z + xrB[4*k+3] * w4.w;
            }
            const float btv = bt[h];
            const float gA = fmaxf(a + btv, 0.f), gB = fmaxf(c + btv, 0.f);
            const float4* wfp = (const float4*)(wf + h * 36);
            #pragma unroll
            for (int k = 0; k < 9; ++k) {
                float4 w4 = wfp[k];
                dpA[4*k]   += gA * w4.x; dpA[4*k+1] += gA * w4.y;
                dpA[4*k+2] += gA * w4.z; dpA[4*k+3] += gA * w4.w;
                dpB[4*k]   += gB * w4.x; dpB[4*k+1] += gB * w4.y;
                dpB[4*k+2] += gB * w4.z; dpB[4*k+3] += gB * w4.w;
            }
        }
        __syncthreads();    // wt/wf weights fully consumed -> pl overlay safe
        float* pl = wt;     // pl[8][32][34] = 8704 floats <= 9216
        #pragma unroll
        for (int j = 0; j < ATOM; ++j) {
            float a = dpA[j];
            a += __shfl_xor(a, 16, 64); a += __shfl_xor(a, 32, 64);
            float c = dpB[j];
            c += __shfl_xor(c, 16, 64); c += __shfl_xor(c, 32, 64);
            if (s2 == 0) {
                pl[(waveU * 32 + rp) * ATOM + j]      = a;
                pl[(waveU * 32 + rp + 16) * ATOM + j] = c;
            }
        }
    }
    __syncthreads();

    // d = sum_w(pl) + bf + xs ; store transposed
    {
        float* pl = wt;
        const float* xsq = xs + b * NA + p0 * ATOM;
        for (int i = t; i < 32 * ATOM; i += 512) {
            int rr = i / ATOM, j = i - rr * ATOM;
            float dv = bf[j] + xsq[rr * ATOM + j];
            #pragma unroll
            for (int w = 0; w < 8; ++w) dv += pl[(w * 32 + rr) * ATOM + j];
            dlT[j * 33 + rr] = dv;
        }
    }
    __syncthreads();

    // d @ Wf2 + bf2 ; partial col-max (4 chunks x 8 rows); Wf2 from L2, coalesced
    {
        const int l = t & 127, chunk = t >> 7;
        float w2r[ATOM];
        #pragma unroll
        for (int j = 0; j < ATOM; ++j) w2r[j] = Wf2[j * LATENT + l];
        const float bb = bf2[l];
        float mx = -3.4e38f;
        #pragma unroll
        for (int r8 = 0; r8 < 8; ++r8) {
            const int rr = chunk * 8 + r8;
            float acc = bb;
            #pragma unroll
            for (int j = 0; j < ATOM; ++j) acc += dlT[j * 33 + rr] * w2r[j];
            mx = fmaxf(mx, acc);
        }
        sl[chunk * 128 + l] = mx;
    }
    __syncthreads();
    if (t < LATENT)
        DM[(b * 4 + q4) * LATENT + t] =
            fmaxf(fmaxf(sl[t], sl[128 + t]), fmaxf(sl[256 + t], sl[384 + t]));
}

// ---------------- K3: full decoder, k-split partial sums ----------------
__global__ __launch_bounds__(1024) void k_dec(
    const float* __restrict__ DM, const float* __restrict__ cell,
    const float* __restrict__ W1, const float* __restrict__ b1,
    const float* __restrict__ W2, const float* __restrict__ b2,
    const float* __restrict__ W3, const float* __restrict__ b3,
    const float* __restrict__ W4, const float* __restrict__ b4,
    float* __restrict__ out)
{
    const int b = blockIdx.x, t = threadIdx.x, lane = t & 63, wave = t >> 6;
    __shared__ float vec[LATENT + CELLS];
    __shared__ float h1[128], h2[256], h3[512];
    __shared__ float sl[1024];
    if (t < LATENT) {
        float m = fmaxf(fmaxf(DM[(b*4+0)*LATENT + t], DM[(b*4+1)*LATENT + t]),
                        fmaxf(DM[(b*4+2)*LATENT + t], DM[(b*4+3)*LATENT + t]));
        vec[t] = 1.f / (1.f + __expf(-m));
    } else if (t >= 512) {
        int c = t - 512;
        vec[LATENT + c] = 1.f / (1.f + __expf(-cell[b * CELLS + c]));
    }
    __syncthreads();
    {
        const int j = t & 127, part = t >> 7;
        float acc = 0.f;
        #pragma unroll 4
        for (int k = part * 80; k < part * 80 + 80; ++k)
            acc += vec[k] * W1[k * 128 + j];
        sl[part * 128 + j] = acc;
    }
    __syncthreads();
    if (t < 128) {
        float v = b1[t];
        #pragma unroll
        for (int p = 0; p < 8; ++p) v += sl[p * 128 + t];
        h1[t] = fmaxf(v, 0.f);
    }
    __syncthreads();
    {
        const int j = t & 255, part = t >> 8;
        float acc = 0.f;
        #pragma unroll 4
        for (int k = part * 32; k < part * 32 + 32; ++k)
            acc += h1[k] * W2[k * 256 + j];
        sl[part * 256 + j] = acc;
    }
    __syncthreads();
    if (t < 256) h2[t] = fmaxf(sl[t] + sl[256 + t] + sl[512 + t] + sl[768 + t] + b2[t], 0.f);
    __syncthreads();
    {
        const int j = t & 511, part = t >> 9;
        float acc = 0.f;
        #pragma unroll 4
        for (int k = part * 128; k < part * 128 + 128; ++k)
            acc += h2[k] * W3[k * 512 + j];
        sl[part * 512 + j] = acc;
    }
    __syncthreads();
    if (t < 512) h3[t] = fmaxf(sl[t] + sl[512 + t] + b3[t], 0.f);
    __syncthreads();
    float v = (t < 512) ? h3[t] * W4[t] : 0.f;
    #pragma unroll
    for (int o = 32; o >= 1; o >>= 1) v += __shfl_xor(v, o, 64);
    if (lane == 0) sl[wave] = v;
    __syncthreads();
    if (t == 0) {
        float s = b4[0];
        #pragma unroll
        for (int w = 0; w < 16; ++w) s += sl[w];
        out[b] = s;
    }
}

extern "C" void kernel_launch(void* const* d_in, const int* in_sizes, int n_in,
                              void* d_out, int out_size, void* d_ws, size_t ws_size,
                              hipStream_t stream) {
    const float* xs       = (const float*)d_in[0];
    const int*   A        = (const int*)  d_in[1];
    const float* cell_emb = (const float*)d_in[2];
    const float* Wg       = (const float*)d_in[3];
    const float* bg       = (const float*)d_in[4];
    const float* attnv    = (const float*)d_in[5];
    const float* Wt       = (const float*)d_in[6];
    const float* bt       = (const float*)d_in[7];
    const float* Wf       = (const float*)d_in[8];
    const float* bf       = (const float*)d_in[9];
    const float* Wf2      = (const float*)d_in[10];
    const float* bf2      = (const float*)d_in[11];
    const float* W1       = (const float*)d_in[12];
    const float* b1       = (const float*)d_in[13];
    const float* W2       = (const float*)d_in[14];
    const float* b2       = (const float*)d_in[15];
    const float* W3       = (const float*)d_in[16];
    const float* b3       = (const float*)d_in[17];
    const float* W4       = (const float*)d_in[18];
    const float* b4       = (const float*)d_in[19];
    float* out = (float*)d_out;

    float* Wsp = (float*)d_ws;
    float* X0   = Wsp;                 // 278528
    float* X1   = Wsp + 278528;        // 278528
    float* DM   = Wsp + 557056;        // 32768
    unsigned long long* Mm = (unsigned long long*)(Wsp + 589824);  // 16384 u64 (byte-off %8==0)
    float* WgT3 = Wsp + 622592;        // 3672

    k_prep<<<65, 256, 0, stream>>>(A, Wg, Mm, WgT3);
    k_gat<<<512, 256, 0, stream>>>(xs, Mm, WgT3,        bg,      attnv,           X0);
    k_gat<<<512, 256, 0, stream>>>(X0, Mm, WgT3 + 1224, bg + 34, attnv + 68,      X1);
    k_gat<<<512, 256, 0, stream>>>(X1, Mm, WgT3 + 2448, bg + 68, attnv + 136,     X0);
    k_phaseB<<<256, 512, 0, stream>>>(X0, xs, Wt, bt, Wf, bf, Wf2, bf2, DM);
    k_dec<<<64, 1024, 0, stream>>>(DM, cell_emb, W1, b1, W2, b2, W3, b3, W4, b4, out);
}